// Round 7
// baseline (235.189 us; speedup 1.0000x reference)
//
#include <hip/hip_runtime.h>
#include <stdint.h>

// RNN: h_{t+1} = tanh(x_t @ W_ih^T + b_ih + b_hh + h_t @ W_hh^T), out = h_T @ fc_w^T + fc_b
// B=8192, T=512, IN=8, H=16.
//
// Zero-cross-lane MFMA recurrence (round-5/6 structure), minimal-chain edition.
// One wave owns 16 elements; quarter q (lane>>4) owns D units 4q..4q+3 AND supplies
// the B k-slots that carry those same units' state -> D feeds B directly, the MFMA
// K-reduction does the cross-lane sum. V = -2c*W_hh, U = c*W_ih (c = 2*log2 e),
// state r = 1/(exp2(c*s)+1), tanh affine folded into V/bias (h = 1-2r).
//
// CHANGES vs round 6 (chain-latency attack #2; 385 cyc/step measured):
//  1. x-projection hoisted OFF the chain: per tile, xp[tt] = U.x + cb is
//     precomputed by 32 independent mfma_f32_16x16x16f16 (throughput-bound,
//     amortized ~8 cyc/step). Per-step MFMA1 takes C = xp[tt].
//  2. MFMA1 is now K=16 (A=Vhi, B={rh0,rh1}): B regs written DIRECTLY by the
//     two cvt_pkrtz -> no B-build movs on the chain, shorter MFMA pipe.
//  3. MFMA2 (K=32, parallel) carries both corrections: Vhi.rl + Vlo.rh
//     (B = {rl0,rl1,rh0,rh1}). Only Vlo.rl (~2^-24) dropped -> numerics
//     identical to round 6 (absmax 0.0039).
// Serial chain: pkh -> MFMA1(K16) -> add -> exp2 -> add -> rcp.  rl path + MFMA2
// converge in parallel (rl ready ~16cyc after r; MFMA2 joins at the add).

#define RNN_B   8192
#define RNN_T   512
#define RNN_IN  8
#define RNN_H   16
#define TC      32                  // timesteps per x tile
#define NE      16                  // batch elements per block (= per wave)
#define XROW    260                 // floats per staged row (256 + 4 pad; 1040B, 16B-aligned)
#define NTILE   (RNN_T / TC)
#define BUFSZ   (NE * XROW)

typedef __fp16 half8  __attribute__((ext_vector_type(8)));
typedef __fp16 half4  __attribute__((ext_vector_type(4)));
typedef __fp16 half2v __attribute__((ext_vector_type(2)));
typedef float  f32x4  __attribute__((ext_vector_type(4)));

union H8U { half8 v; __fp16 e[8]; uint32_t u[4]; };
union H4U { half4 v; __fp16 e[4]; uint32_t u[2]; };
union H2U { half2v h; uint32_t u; };

static __device__ __forceinline__ uint32_t pkh(float a, float b) {
    H2U t; t.h = __builtin_amdgcn_cvt_pkrtz(a, b); return t.u;
}

// Stage one 16-elem x 32-timestep x tile: each row = 256 floats = 1024 B =
// exactly one global_load_lds (64 lanes x 16 B), wave-uniform LDS base per row.
static __device__ __forceinline__ void stage(const float* __restrict__ x,
                                             float* lds_base, int b0, int t0,
                                             int lane)
{
#pragma unroll
    for (int e = 0; e < NE; ++e) {
        const float* gp = x + ((size_t)(b0 + e) * RNN_T + t0) * RNN_IN + lane * 4;
        float* lp = lds_base + e * XROW;
        __builtin_amdgcn_global_load_lds(
            (const __attribute__((address_space(1))) uint32_t*)gp,
            (__attribute__((address_space(3))) uint32_t*)lp,
            16, 0, 0);
    }
}

__global__ __launch_bounds__(64) void rnn_mfma_kernel(
    const float* __restrict__ x,     // [B, T, IN]
    const float* __restrict__ W_ih,  // [H, IN]
    const float* __restrict__ W_hh,  // [H, H]
    const float* __restrict__ b_ih,  // [H]
    const float* __restrict__ b_hh,  // [H]
    const float* __restrict__ fc_w,  // [1, H]
    const float* __restrict__ fc_b,  // [1]
    float* __restrict__ out)         // [B, 1]
{
    __shared__ __align__(16) float xs[2 * BUFSZ];   // 33.3 KB double-buffered x

    const int lane = (int)threadIdx.x;   // 0..63
    const int col  = lane & 15;          // elem (B/D col) AND A-row (output unit m)
    const int q    = lane >> 4;          // lane quarter: owns D units 4q..4q+3
    const int b0   = (int)blockIdx.x * NE;
    const float C2 = 2.8853900817779268f;   // 2*log2(e)

    // ---- A fragments.
    // MFMA1 (16x16x16): k-slot 4q+j  -> A1.e[j] = Vhi[col][4q+j]          (x rh)
    // MFMA2 (16x16x32): k-slot 8q+j  -> j<4: Vhi[col][4q+j] (x rl)
    //                                   j>=4: Vlo[col][4q+(j-4)] (x rh)
    // Ax    (16x16x16): k-slot 4q+j  -> j<2: Uhi[col][2q+j] (x x)
    //                                   j>=2: Ulo[col][2q+(j-2)] (x x)
    H4U A1, Ax;
    H8U A2;
#pragma unroll
    for (int j = 0; j < 4; ++j) {
        const int u = 4 * q + j;
        const float v = -2.0f * C2 * W_hh[col * RNN_H + u];
        const __fp16 vh = (__fp16)v;
        const __fp16 vl = (__fp16)(v - (float)vh);
        A1.e[j]     = vh;
        A2.e[j]     = vh;   // x rl
        A2.e[4 + j] = vl;   // x rh
    }
#pragma unroll
    for (int j = 0; j < 2; ++j) {
        const int f = 2 * q + j;
        const float uu = C2 * W_ih[col * RNN_IN + f];
        const __fp16 uh = (__fp16)uu;
        Ax.e[j]     = uh;                        // Uhi
        Ax.e[2 + j] = (__fp16)(uu - (float)uh);  // Ulo
    }

    // ---- C bias: D rows = units 4q+rr.  cb = c*(b_ih+b_hh) - 0.5*rowsum(Vhi+Vlo)
    f32x4 cb;
#pragma unroll
    for (int rr = 0; rr < 4; ++rr) {
        const int u = 4 * q + rr;
        float s = 0.0f;
        for (int k = 0; k < RNN_H; ++k) {
            const float v = -2.0f * C2 * W_hh[u * RNN_H + k];
            const __fp16 vh = (__fp16)v;
            const __fp16 vl = (__fp16)(v - (float)vh);
            s += (float)vh + (float)vl;
        }
        cb[rr] = C2 * (b_ih[u] + b_hh[u]) - 0.5f * s;
    }
    const f32x4 zero4 = {0.0f, 0.0f, 0.0f, 0.0f};

    // prologue: tile 0 -> buffer 0
    stage(x, xs, b0, 0, lane);
    __syncthreads();

    // state r = 0.5 (h0 = 0); fp16(0.5) exact -> lo residual = 0
    uint32_t rh0 = pkh(0.5f, 0.5f), rh1 = pkh(0.5f, 0.5f);
    uint32_t rl0 = 0u, rl1 = 0u;

    for (int tile = 0; tile < NTILE; ++tile) {
        const int cur = tile & 1;

        // ---- OFF-CHAIN: read tile's x and project through U via 32 independent
        // K=16 MFMAs: xp[tt] = U.x_tt + cb. Fully unrolled -> static reg indexing.
        const float* xg = xs + cur * BUFSZ + col * XROW + 2 * q;
        f32x4 xp[TC];
#pragma unroll
        for (int tt = 0; tt < TC; ++tt) {
            const float2 xf = *(const float2*)(xg + tt * 8);
            H4U Bx;
            Bx.u[0] = pkh(xf.x, xf.y);
            Bx.u[1] = Bx.u[0];
            xp[tt] = __builtin_amdgcn_mfma_f32_16x16x16f16(Ax.v, Bx.v, cb, 0, 0, 0);
        }

        // issue next tile's async staging; drained by the end-of-tile barrier
        if (tile + 1 < NTILE)
            stage(x, xs + (cur ^ 1) * BUFSZ, b0, (tile + 1) * TC, lane);

        // ---- 32 minimal-chain recurrence steps (pure register work)
#pragma unroll
        for (int tt = 0; tt < TC; ++tt) {
            H4U B1;                       // {rh0, rh1} -- written straight by pkh
            B1.u[0] = rh0; B1.u[1] = rh1;
            H8U B2;                       // {rl0, rl1, rh0, rh1}
            B2.u[0] = rl0; B2.u[1] = rl1; B2.u[2] = rh0; B2.u[3] = rh1;

            const f32x4 ac1 = __builtin_amdgcn_mfma_f32_16x16x16f16(A1.v, B1.v, xp[tt], 0, 0, 0);
            const f32x4 ac2 = __builtin_amdgcn_mfma_f32_16x16x32_f16(A2.v, B2.v, zero4, 0, 0, 0);

            // r = 1/(exp2(S)+1), S pre-scaled by c; 4 independent lanes of chain
            const float r0 = __builtin_amdgcn_rcpf(__builtin_amdgcn_exp2f(ac1[0] + ac2[0]) + 1.0f);
            const float r1 = __builtin_amdgcn_rcpf(__builtin_amdgcn_exp2f(ac1[1] + ac2[1]) + 1.0f);
            const float r2 = __builtin_amdgcn_rcpf(__builtin_amdgcn_exp2f(ac1[2] + ac2[2]) + 1.0f);
            const float r3 = __builtin_amdgcn_rcpf(__builtin_amdgcn_exp2f(ac1[3] + ac2[3]) + 1.0f);

            // hi/lo split of the state (residual compensation)
            rh0 = pkh(r0, r1); rh1 = pkh(r2, r3);
            H2U u0, u1; u0.u = rh0; u1.u = rh1;
            rl0 = pkh(r0 - (float)u0.h[0], r1 - (float)u0.h[1]);
            rl1 = pkh(r2 - (float)u1.h[0], r3 - (float)u1.h[1]);
        }
        __syncthreads();   // drains next-tile global_load_lds + fences LDS reuse
    }

    // ---- epilogue: h = 1 - 2(r_hi + r_lo); out[elem] = sum_u fc_w[u]*h_u + fc_b
    H2U a0, a1, c0, c1;
    a0.u = rh0; a1.u = rh1; c0.u = rl0; c1.u = rl1;
    const float h0 = 1.0f - 2.0f * ((float)a0.h[0] + (float)c0.h[0]);
    const float h1 = 1.0f - 2.0f * ((float)a0.h[1] + (float)c0.h[1]);
    const float h2 = 1.0f - 2.0f * ((float)a1.h[0] + (float)c1.h[0]);
    const float h3 = 1.0f - 2.0f * ((float)a1.h[1] + (float)c1.h[1]);
    float p = fc_w[4 * q + 0] * h0 + fc_w[4 * q + 1] * h1
            + fc_w[4 * q + 2] * h2 + fc_w[4 * q + 3] * h3;
    p += __shfl_xor(p, 16);
    p += __shfl_xor(p, 32);
    if (lane < 16) out[b0 + col] = p + fc_b[0];
}

extern "C" void kernel_launch(void* const* d_in, const int* in_sizes, int n_in,
                              void* d_out, int out_size, void* d_ws, size_t ws_size,
                              hipStream_t stream)
{
    const float* x    = (const float*)d_in[0];
    const float* W_ih = (const float*)d_in[1];
    const float* W_hh = (const float*)d_in[2];
    const float* b_ih = (const float*)d_in[3];
    const float* b_hh = (const float*)d_in[4];
    const float* fc_w = (const float*)d_in[5];
    const float* fc_b = (const float*)d_in[6];
    float* out = (float*)d_out;

    dim3 grid(RNN_B / NE);   // 512 blocks x 64 threads
    dim3 block(64);
    rnn_mfma_kernel<<<grid, block, 0, stream>>>(x, W_ih, W_hh, b_ih, b_hh, fc_w, fc_b, out);
}

// Round 8
// 217.413 us; speedup vs baseline: 1.0818x; 1.0818x over previous
//
#include <hip/hip_runtime.h>
#include <stdint.h>

// RNN: h_{t+1} = tanh(x_t @ W_ih^T + b_ih + b_hh + h_t @ W_hh^T), out = h_T @ fc_w^T + fc_b
// B=8192, T=512, IN=8, H=16.
//
// Zero-cross-lane MFMA recurrence. One wave owns 16 elements; quarter q (lane>>4)
// owns D units 4q..4q+3 AND supplies the B k-slots carrying those units' state ->
// D feeds B directly; the MFMA K-reduction does the cross-lane sum.
// V = -2c*W_hh, U = c*W_ih (c = 2*log2 e); state r = 1/(exp2(c*s)+1); tanh affine
// h = 1-2r folded into V and bias. fp16 hi/lo residual compensation (only Vlo*rl,
// ~2^-24, dropped) -- term set identical to round 6 (absmax 0.0039).
//
// ROUND 8 = round-6 codegen + round-7 chain, no big arrays:
//  - xq[32] packed-x prefetch (1 VGPR/step, proven no-spill in R6).
//  - MFMA1 is K=16: A=Vhi, B={rh0,rh1} written DIRECTLY by the two on-chain
//    cvt_pkrtz; C = acx (x-projection + bias) enters via the accumulator port.
//  - acx = mfma16(Ux, {xq,xq}, cb) pipelined ONE STEP AHEAD as an explicit SSA
//    variable (not an array -> no spill, no compiler loop-fusion surprise).
//  - MFMA2 (K=32, parallel, off-chain): Vhi*rl + Vlo*rh, C=0.  S = ac1 + ac2.
// Serial chain: pkh -> MFMA1(K16) -> add -> exp2 -> add -> rcp.

#define RNN_B   8192
#define RNN_T   512
#define RNN_IN  8
#define RNN_H   16
#define TC      32                  // timesteps per x tile
#define NE      16                  // batch elements per block (= per wave)
#define XROW    260                 // floats per staged row (256 + 4 pad; 1040B, 16B-aligned)
#define NTILE   (RNN_T / TC)
#define BUFSZ   (NE * XROW)

typedef __fp16 half8  __attribute__((ext_vector_type(8)));
typedef __fp16 half4  __attribute__((ext_vector_type(4)));
typedef __fp16 half2v __attribute__((ext_vector_type(2)));
typedef float  f32x4  __attribute__((ext_vector_type(4)));

union H8U { half8 v; __fp16 e[8]; uint32_t u[4]; };
union H4U { half4 v; __fp16 e[4]; uint32_t u[2]; };
union H2U { half2v h; uint32_t u; };

static __device__ __forceinline__ uint32_t pkh(float a, float b) {
    H2U t; t.h = __builtin_amdgcn_cvt_pkrtz(a, b); return t.u;
}

// Stage one 16-elem x 32-timestep x tile: each row = 256 floats = 1024 B =
// exactly one global_load_lds (64 lanes x 16 B), wave-uniform LDS base per row.
static __device__ __forceinline__ void stage(const float* __restrict__ x,
                                             float* lds_base, int b0, int t0,
                                             int lane)
{
#pragma unroll
    for (int e = 0; e < NE; ++e) {
        const float* gp = x + ((size_t)(b0 + e) * RNN_T + t0) * RNN_IN + lane * 4;
        float* lp = lds_base + e * XROW;
        __builtin_amdgcn_global_load_lds(
            (const __attribute__((address_space(1))) uint32_t*)gp,
            (__attribute__((address_space(3))) uint32_t*)lp,
            16, 0, 0);
    }
}

__global__ __launch_bounds__(64) void rnn_mfma_kernel(
    const float* __restrict__ x,     // [B, T, IN]
    const float* __restrict__ W_ih,  // [H, IN]
    const float* __restrict__ W_hh,  // [H, H]
    const float* __restrict__ b_ih,  // [H]
    const float* __restrict__ b_hh,  // [H]
    const float* __restrict__ fc_w,  // [1, H]
    const float* __restrict__ fc_b,  // [1]
    float* __restrict__ out)         // [B, 1]
{
    __shared__ __align__(16) float xs[2 * BUFSZ];   // 33.3 KB double-buffered x

    const int lane = (int)threadIdx.x;   // 0..63
    const int col  = lane & 15;          // elem (B/D col) AND A-row (output unit m)
    const int q    = lane >> 4;          // lane quarter: owns D units 4q..4q+3
    const int b0   = (int)blockIdx.x * NE;
    const float C2 = 2.8853900817779268f;   // 2*log2(e)

    // ---- A fragments.
    // MFMA1 (16x16x16): k-slot 4q+j -> A1.e[j] = Vhi[col][4q+j]        (x rh)
    // MFMA2 (16x16x32): k-slot 8q+j -> j<4: Vhi[col][4q+j]             (x rl)
    //                                  j>=4: Vlo[col][4q+(j-4)]        (x rh)
    // Ax    (16x16x16): k-slot 4q+j -> j<2: Uhi[col][2q+j], j>=2: Ulo  (x x)
    H4U A1, Ax;
    H8U A2;
#pragma unroll
    for (int j = 0; j < 4; ++j) {
        const int u = 4 * q + j;
        const float v = -2.0f * C2 * W_hh[col * RNN_H + u];
        const __fp16 vh = (__fp16)v;
        const __fp16 vl = (__fp16)(v - (float)vh);
        A1.e[j]     = vh;
        A2.e[j]     = vh;   // x rl
        A2.e[4 + j] = vl;   // x rh
    }
#pragma unroll
    for (int j = 0; j < 2; ++j) {
        const int f = 2 * q + j;
        const float uu = C2 * W_ih[col * RNN_IN + f];
        const __fp16 uh = (__fp16)uu;
        Ax.e[j]     = uh;                        // Uhi
        Ax.e[2 + j] = (__fp16)(uu - (float)uh);  // Ulo
    }

    // ---- C bias: D rows = units 4q+rr.  cb = c*(b_ih+b_hh) - 0.5*rowsum(Vhi+Vlo)
    f32x4 cb;
#pragma unroll
    for (int rr = 0; rr < 4; ++rr) {
        const int u = 4 * q + rr;
        float s = 0.0f;
        for (int k = 0; k < RNN_H; ++k) {
            const float v = -2.0f * C2 * W_hh[u * RNN_H + k];
            const __fp16 vh = (__fp16)v;
            const __fp16 vl = (__fp16)(v - (float)vh);
            s += (float)vh + (float)vl;
        }
        cb[rr] = C2 * (b_ih[u] + b_hh[u]) - 0.5f * s;
    }
    const f32x4 zero4 = {0.0f, 0.0f, 0.0f, 0.0f};

    // prologue: tile 0 -> buffer 0
    stage(x, xs, b0, 0, lane);
    __syncthreads();

    // state r = 0.5 (h0 = 0); fp16(0.5) exact -> lo residual = 0
    uint32_t rh0 = pkh(0.5f, 0.5f), rh1 = pkh(0.5f, 0.5f);
    uint32_t rl0 = 0u, rl1 = 0u;

    for (int tile = 0; tile < NTILE; ++tile) {
        const int cur = tile & 1;

        // ---- x pack prefetch: 1 VGPR per step (R6 codegen, proven no-spill).
        const float* xg = xs + cur * BUFSZ + col * XROW + 2 * q;
        uint32_t xq[TC];
#pragma unroll
        for (int tt = 0; tt < TC; ++tt) {
            const float2 xf = *(const float2*)(xg + tt * 8);
            xq[tt] = pkh(xf.x, xf.y);
        }

        // issue next tile's async staging; drained by the end-of-tile barrier
        if (tile + 1 < NTILE)
            stage(x, xs + (cur ^ 1) * BUFSZ, b0, (tile + 1) * TC, lane);

        // ---- x-projection pipeline, 1 step ahead: acx = U.x + cb
        H4U Bx0; Bx0.u[0] = xq[0]; Bx0.u[1] = xq[0];
        f32x4 acx = __builtin_amdgcn_mfma_f32_16x16x16f16(Ax.v, Bx0.v, cb, 0, 0, 0);

        // ---- 32 minimal-chain recurrence steps (pure register work)
#pragma unroll
        for (int tt = 0; tt < TC; ++tt) {
            // prefetch next step's x-projection (independent; hides under chain)
            f32x4 acx_next = acx;
            if (tt + 1 < TC) {
                H4U Bxn; Bxn.u[0] = xq[tt + 1]; Bxn.u[1] = xq[tt + 1];
                acx_next = __builtin_amdgcn_mfma_f32_16x16x16f16(Ax.v, Bxn.v, cb, 0, 0, 0);
            }

            H4U B1;                       // {rh0, rh1} -- written straight by pkh
            B1.u[0] = rh0; B1.u[1] = rh1;
            H8U B2;                       // {rl0, rl1, rh0, rh1}
            B2.u[0] = rl0; B2.u[1] = rl1; B2.u[2] = rh0; B2.u[3] = rh1;

            // chain MFMA: Vhi.rh + (x-proj via accumulator port)
            const f32x4 ac1 = __builtin_amdgcn_mfma_f32_16x16x16f16(A1.v, B1.v, acx, 0, 0, 0);
            // parallel correction MFMA: Vhi.rl + Vlo.rh
            const f32x4 ac2 = __builtin_amdgcn_mfma_f32_16x16x32_f16(A2.v, B2.v, zero4, 0, 0, 0);

            // r = 1/(exp2(S)+1), S pre-scaled by c
            const float r0 = __builtin_amdgcn_rcpf(__builtin_amdgcn_exp2f(ac1[0] + ac2[0]) + 1.0f);
            const float r1 = __builtin_amdgcn_rcpf(__builtin_amdgcn_exp2f(ac1[1] + ac2[1]) + 1.0f);
            const float r2 = __builtin_amdgcn_rcpf(__builtin_amdgcn_exp2f(ac1[2] + ac2[2]) + 1.0f);
            const float r3 = __builtin_amdgcn_rcpf(__builtin_amdgcn_exp2f(ac1[3] + ac2[3]) + 1.0f);

            // hi/lo split of the state (residual compensation)
            rh0 = pkh(r0, r1); rh1 = pkh(r2, r3);
            H2U u0, u1; u0.u = rh0; u1.u = rh1;
            rl0 = pkh(r0 - (float)u0.h[0], r1 - (float)u0.h[1]);
            rl1 = pkh(r2 - (float)u1.h[0], r3 - (float)u1.h[1]);

            acx = acx_next;
        }
        __syncthreads();   // drains next-tile global_load_lds + fences LDS reuse
    }

    // ---- epilogue: h = 1 - 2(r_hi + r_lo); out[elem] = sum_u fc_w[u]*h_u + fc_b
    H2U a0, a1, c0, c1;
    a0.u = rh0; a1.u = rh1; c0.u = rl0; c1.u = rl1;
    const float h0 = 1.0f - 2.0f * ((float)a0.h[0] + (float)c0.h[0]);
    const float h1 = 1.0f - 2.0f * ((float)a0.h[1] + (float)c0.h[1]);
    const float h2 = 1.0f - 2.0f * ((float)a1.h[0] + (float)c1.h[0]);
    const float h3 = 1.0f - 2.0f * ((float)a1.h[1] + (float)c1.h[1]);
    float p = fc_w[4 * q + 0] * h0 + fc_w[4 * q + 1] * h1
            + fc_w[4 * q + 2] * h2 + fc_w[4 * q + 3] * h3;
    p += __shfl_xor(p, 16);
    p += __shfl_xor(p, 32);
    if (lane < 16) out[b0 + col] = p + fc_b[0];
}

extern "C" void kernel_launch(void* const* d_in, const int* in_sizes, int n_in,
                              void* d_out, int out_size, void* d_ws, size_t ws_size,
                              hipStream_t stream)
{
    const float* x    = (const float*)d_in[0];
    const float* W_ih = (const float*)d_in[1];
    const float* W_hh = (const float*)d_in[2];
    const float* b_ih = (const float*)d_in[3];
    const float* b_hh = (const float*)d_in[4];
    const float* fc_w = (const float*)d_in[5];
    const float* fc_b = (const float*)d_in[6];
    float* out = (float*)d_out;

    dim3 grid(RNN_B / NE);   // 512 blocks x 64 threads
    dim3 block(64);
    rnn_mfma_kernel<<<grid, block, 0, stream>>>(x, W_ih, W_hh, b_ih, b_hh, fc_w, fc_b, out);
}